// Round 13
// baseline (949.656 us; speedup 1.0000x reference)
//
#include <hip/hip_runtime.h>
#include <stdint.h>

// B=4, S=2048, D=1024, H=16, HD=64. All inputs fp32.
// convert->bf16; Q(pre-scaled by 0.125*log2e),K in [B,H,S,HD]; V^T [B,H,HD,S];
// flash attention (4 waves x 64 q-rows per block, 2 blocks/CU = 4 waves/SIMD;
// 32x32 MFMA swapped QK^T; swap23-permuted K staging -> PV A-frags lane-local;
// register softmax, MFMA denominator, dbuf K/V, XCD swizzle) -> ao bf16;
// out = ao@wo^T+bo fp32.

#define B_ 4
#define S_ 2048
#define D_ 1024
#define H_ 16
#define HD_ 64
#define M_ (B_ * S_)

typedef __bf16 bf16x8 __attribute__((ext_vector_type(8)));
typedef float f32x4 __attribute__((ext_vector_type(4)));
typedef float f32x16 __attribute__((ext_vector_type(16)));
typedef unsigned short u16;
typedef union { bf16x8 v; unsigned u[4]; } bfu;

// 0.125 (1/sqrt(HD)) * log2(e): scores come out in log2 units
#define QSCALE 0.18033688011112042f
#define THR2 11.0f  // defer-max threshold in log2 units

__device__ __forceinline__ u16 f2bf(float f) {
  union { float f; unsigned u; } v; v.f = f;
  unsigned u = v.u;
  u += 0x7fff + ((u >> 16) & 1);
  return (u16)(u >> 16);
}

__device__ __forceinline__ float exp2_fast(float x) {
#if __has_builtin(__builtin_amdgcn_exp2f)
  return __builtin_amdgcn_exp2f(x);
#else
  return __expf(x * 0.69314718056f);
#endif
}

__device__ __forceinline__ unsigned packbf(float a, float b) {
  union { unsigned u; __bf16 h[2]; } v;
  v.h[0] = (__bf16)a; v.h[1] = (__bf16)b;
  return v.u;
}

__device__ __forceinline__ void gl2lds16(const void* g, void* l) {
  __builtin_amdgcn_global_load_lds(
      (const __attribute__((address_space(1))) unsigned int*)g,
      (__attribute__((address_space(3))) unsigned int*)l, 16, 0, 0);
}

// ---------------- convert fp32 -> bf16 ----------------
__global__ __launch_bounds__(256) void convert_kernel(
    const float* __restrict__ x, const float* __restrict__ wq,
    const float* __restrict__ wk, const float* __restrict__ wv,
    const float* __restrict__ wo, u16* __restrict__ xb, u16* __restrict__ wqb,
    u16* __restrict__ wkb, u16* __restrict__ wvb, u16* __restrict__ wob) {
  const int64_t NX = (int64_t)M_ * D_ / 4;
  const int64_t NW = (int64_t)D_ * D_ / 4;
  int64_t i = (int64_t)blockIdx.x * blockDim.x + threadIdx.x;
  const float* src; u16* dst; int64_t off;
  if (i < NX)              { src = x;  dst = xb;  off = i; }
  else if (i < NX + NW)    { src = wq; dst = wqb; off = i - NX; }
  else if (i < NX + 2*NW)  { src = wk; dst = wkb; off = i - NX - NW; }
  else if (i < NX + 3*NW)  { src = wv; dst = wvb; off = i - NX - 2*NW; }
  else                     { src = wo; dst = wob; off = i - NX - 3*NW; }
  float4 v = reinterpret_cast<const float4*>(src)[off];
  ushort4 o;
  o.x = f2bf(v.x); o.y = f2bf(v.y); o.z = f2bf(v.z); o.w = f2bf(v.w);
  reinterpret_cast<ushort4*>(dst)[off] = o;
}

// ---------------- bf16 MFMA GEMM: C = A(MxK) @ Bw(NxK)^T + bias ----------------
// MODE 0: bf16 out [B,H,S,HD] (K proj)   MODE 3: same, scaled by QSCALE (Q proj)
// MODE 1: swapped, bf16 out [B,H,HD,S] (V^T)   MODE 2: fp32 out [M,N] (final)
template <int MODE>
__global__ __launch_bounds__(256) void gemm_kernel(
    const u16* __restrict__ A, const u16* __restrict__ Bw,
    const float* __restrict__ bias, void* __restrict__ out) {
  __shared__ u16 As[128 * 64];
  __shared__ u16 Bs[128 * 64];
  const int tid = threadIdx.x;
  const int lane = tid & 63;
  const int wid = tid >> 6;
  const int row0 = blockIdx.y * 128;
  const int col0 = blockIdx.x * 128;
  const int wr = (wid >> 1) * 64;
  const int wc = (wid & 1) * 64;

  f32x4 acc[4][4] = {};
  const int srow = lane >> 3;
  const int cc = (lane & 7) ^ srow;

  for (int kt = 0; kt < D_; kt += 64) {
    __syncthreads();
    for (int t = 0; t < 4; ++t) {
      int r = (wid * 4 + t) * 8 + srow;
      gl2lds16(A + (int64_t)(row0 + r) * D_ + kt + cc * 8,
               (char*)As + (wid * 4 + t) * 1024);
      gl2lds16(Bw + (int64_t)(col0 + r) * D_ + kt + cc * 8,
               (char*)Bs + (wid * 4 + t) * 1024);
    }
    __syncthreads();

    bf16x8 af[4][2], bfr[4][2];
#pragma unroll
    for (int mi = 0; mi < 4; ++mi)
#pragma unroll
      for (int ks = 0; ks < 2; ++ks) {
        int c = ks * 4 + (lane >> 4);
        int ra = wr + mi * 16 + (lane & 15);
        af[mi][ks] = *reinterpret_cast<const bf16x8*>(
            (char*)As + ra * 128 + ((c ^ (ra & 7)) << 4));
        int rb = wc + mi * 16 + (lane & 15);
        bfr[mi][ks] = *reinterpret_cast<const bf16x8*>(
            (char*)Bs + rb * 128 + ((c ^ (rb & 7)) << 4));
      }
#pragma unroll
    for (int ks = 0; ks < 2; ++ks)
#pragma unroll
      for (int mi = 0; mi < 4; ++mi)
#pragma unroll
        for (int ni = 0; ni < 4; ++ni) {
          if (MODE == 1)
            acc[mi][ni] = __builtin_amdgcn_mfma_f32_16x16x32_bf16(
                bfr[ni][ks], af[mi][ks], acc[mi][ni], 0, 0, 0);
          else
            acc[mi][ni] = __builtin_amdgcn_mfma_f32_16x16x32_bf16(
                af[mi][ks], bfr[ni][ks], acc[mi][ni], 0, 0, 0);
        }
  }

  if (MODE == 0 || MODE == 3) {
    u16* o = (u16*)out;
#pragma unroll
    for (int mi = 0; mi < 4; ++mi)
#pragma unroll
      for (int ni = 0; ni < 4; ++ni) {
        int j = col0 + wc + ni * 16 + (lane & 15);
        float bvv = bias[j];
        int h = j >> 6, hd = j & 63;
#pragma unroll
        for (int r = 0; r < 4; ++r) {
          int i = row0 + wr + mi * 16 + (lane >> 4) * 4 + r;
          int b = i >> 11, s = i & 2047;
          float val = acc[mi][ni][r] + bvv;
          if (MODE == 3) val *= QSCALE;
          o[((int64_t)(b * H_ + h) * S_ + s) * HD_ + hd] = f2bf(val);
        }
      }
  } else if (MODE == 1) {
    u16* o = (u16*)out;
#pragma unroll
    for (int mi = 0; mi < 4; ++mi)
#pragma unroll
      for (int ni = 0; ni < 4; ++ni) {
        int i = row0 + wr + mi * 16 + (lane & 15);
        int b = i >> 11, s = i & 2047;
#pragma unroll
        for (int r = 0; r < 4; ++r) {
          int j = col0 + wc + ni * 16 + (lane >> 4) * 4 + r;
          int h = j >> 6, hd = j & 63;
          o[((int64_t)(b * H_ + h) * HD_ + hd) * S_ + s] = f2bf(acc[mi][ni][r] + bias[j]);
        }
      }
  } else {
    float* o = (float*)out;
#pragma unroll
    for (int mi = 0; mi < 4; ++mi)
#pragma unroll
      for (int ni = 0; ni < 4; ++ni) {
        int j = col0 + wc + ni * 16 + (lane & 15);
        float bvv = bias[j];
#pragma unroll
        for (int r = 0; r < 4; ++r) {
          int i = row0 + wr + mi * 16 + (lane >> 4) * 4 + r;
          o[(int64_t)i * D_ + j] = acc[mi][ni][r] + bvv;
        }
      }
  }
}

// ---------------- flash attention (4 waves x 64 q-rows, 2 blocks/CU) ----------
// grid 512 (XCD-swizzled: 8 bh per XCD -> KV ~4MB L2-resident). Wave owns 64
// q-rows (qb=0,1); swap23-permuted K staging makes PV A-frags lane-local.
__global__ __launch_bounds__(256, 4) void attn_kernel(
    const u16* __restrict__ Q, const u16* __restrict__ Kg,
    const u16* __restrict__ Vt, u16* __restrict__ AO) {
  __shared__ u16 Ks[2][64 * 64];   // swizzled [kv][hd], rows kv-permuted by swap23
  __shared__ u16 Vs[2][64 * 64];   // swizzled [hd][kv], true kv order
  const int tid = threadIdx.x;
  const int lane = tid & 63;
  const int l31 = lane & 31;
  const int hi = lane >> 5;
  const int wid = tid >> 6;        // 0..3
  const int orig = blockIdx.x;     // 512
  const int swz = (orig & 7) * 64 + (orig >> 3);
  const int bh = swz >> 3;
  const int qw = (swz & 7) * 256 + wid * 64;

  // Q as B-operand (32x32x16): qb sub-block q-col = qw + qb*32 + l31
  bf16x8 qf[2][4];
#pragma unroll
  for (int qb = 0; qb < 2; ++qb)
#pragma unroll
    for (int ks = 0; ks < 4; ++ks)
      qf[qb][ks] = *reinterpret_cast<const bf16x8*>(
          Q + ((int64_t)bh * S_ + qw + qb * 32 + l31) * HD_ + ks * 16 + hi * 8);

  bf16x8 ones8;
#pragma unroll
  for (int i = 0; i < 8; ++i) ones8[i] = (__bf16)1.0f;

  f32x16 o0[2] = {}, o1[2] = {}, ls[2] = {};
  float mrow[2] = {-1e30f, -1e30f};

  const int srow = lane >> 3;
  const int cc = (lane & 7) ^ srow;

  // staging: wave wid owns LDS row-groups {2wid, 2wid+1} for K (swap23'd) and V.
  const int lr0 = (wid * 2 + 0) * 8 + srow;
  const int lr1 = (wid * 2 + 1) * 8 + srow;
  const int sr0 = (lr0 & ~12) | ((lr0 & 4) << 1) | ((lr0 & 8) >> 1);  // swap b2,b3
  const int sr1 = (lr1 & ~12) | ((lr1 & 4) << 1) | ((lr1 & 8) >> 1);
  const u16* kp0 = Kg + ((int64_t)bh * S_ + sr0) * HD_ + cc * 8;
  const u16* kp1 = Kg + ((int64_t)bh * S_ + sr1) * HD_ + cc * 8;
  const u16* vp0 = Vt + ((int64_t)bh * HD_ + lr0) * S_ + cc * 8;
  const u16* vp1 = Vt + ((int64_t)bh * HD_ + lr1) * S_ + cc * 8;

  // prologue: stage tile 0 -> buf 0
  gl2lds16(kp0, (char*)Ks[0] + (wid * 2 + 0) * 1024); kp0 += 64 * HD_;
  gl2lds16(kp1, (char*)Ks[0] + (wid * 2 + 1) * 1024); kp1 += 64 * HD_;
  gl2lds16(vp0, (char*)Vs[0] + (wid * 2 + 0) * 1024); vp0 += 64;
  gl2lds16(vp1, (char*)Vs[0] + (wid * 2 + 1) * 1024); vp1 += 64;

  const int NT = S_ / 64;

#define TILE_STEP(T, CUR)                                                      \
  {                                                                            \
    asm volatile("s_waitcnt vmcnt(0)" ::: "memory");                           \
    __builtin_amdgcn_s_barrier();                                              \
    if ((T) + 1 < NT) {                                                        \
      gl2lds16(kp0, (char*)Ks[(CUR) ^ 1] + (wid * 2 + 0) * 1024);              \
      gl2lds16(kp1, (char*)Ks[(CUR) ^ 1] + (wid * 2 + 1) * 1024);              \
      gl2lds16(vp0, (char*)Vs[(CUR) ^ 1] + (wid * 2 + 0) * 1024);              \
      gl2lds16(vp1, (char*)Vs[(CUR) ^ 1] + (wid * 2 + 1) * 1024);              \
      kp0 += 64 * HD_; kp1 += 64 * HD_; vp0 += 64; vp1 += 64;                  \
    }                                                                          \
    f32x16 sc0[2] = {{}, {}}, sc1[2] = {{}, {}};                               \
    {                                                                          \
      const char* kbase = (const char*)Ks[CUR];                                \
      __builtin_amdgcn_s_setprio(1);                                           \
      _Pragma("unroll")                                                        \
      for (int ks = 0; ks < 4; ++ks) {                                         \
        int chunk = 2 * ks + hi;                                               \
        int r0 = l31, r1 = 32 + l31;                                           \
        bf16x8 k0 = *reinterpret_cast<const bf16x8*>(                          \
            kbase + r0 * 128 + ((chunk ^ (r0 & 7)) << 4));                     \
        bf16x8 k1 = *reinterpret_cast<const bf16x8*>(                          \
            kbase + r1 * 128 + ((chunk ^ (r1 & 7)) << 4));                     \
        _Pragma("unroll")                                                      \
        for (int qb = 0; qb < 2; ++qb) {                                       \
          sc0[qb] = __builtin_amdgcn_mfma_f32_32x32x16_bf16(k0, qf[qb][ks],    \
                                                            sc0[qb], 0, 0, 0); \
          sc1[qb] = __builtin_amdgcn_mfma_f32_32x32x16_bf16(k1, qf[qb][ks],    \
                                                            sc1[qb], 0, 0, 0); \
        }                                                                      \
      }                                                                        \
      __builtin_amdgcn_s_setprio(0);                                           \
    }                                                                          \
    float mx[2];                                                               \
    _Pragma("unroll")                                                          \
    for (int qb = 0; qb < 2; ++qb) {                                           \
      float a8[8];                                                             \
      _Pragma("unroll")                                                        \
      for (int i = 0; i < 8; ++i)                                              \
        a8[i] = fmaxf(fmaxf(fmaxf(sc0[qb][2 * i], sc0[qb][2 * i + 1]),         \
                            sc1[qb][2 * i]), sc1[qb][2 * i + 1]);              \
      mx[qb] = fmaxf(fmaxf(fmaxf(fmaxf(a8[0], a8[1]), a8[2]), a8[3]),          \
                     fmaxf(fmaxf(fmaxf(a8[4], a8[5]), a8[6]), a8[7]));         \
    }                                                                          \
    int okd = (mx[0] - mrow[0] <= THR2 && mx[1] - mrow[1] <= THR2) ? 1 : 0;    \
    if (!__all(okd)) {                                                         \
      _Pragma("unroll")                                                        \
      for (int qb = 0; qb < 2; ++qb) {                                         \
        float mxf = fmaxf(mx[qb], __shfl_xor(mx[qb], 32));                     \
        float mnew = fmaxf(mrow[qb], mxf);                                     \
        float al = exp2_fast(mrow[qb] - mnew);                                 \
        mrow[qb] = mnew;                                                       \
        _Pragma("unroll")                                                      \
        for (int tt = 0; tt < 16; ++tt) {                                      \
          float at = __shfl(al, (tt & 3) + 8 * (tt >> 2) + 4 * hi);            \
          o0[qb][tt] *= at; o1[qb][tt] *= at; ls[qb][tt] *= at;                \
        }                                                                      \
      }                                                                        \
    }                                                                          \
    bfu pa[2][4];                                                              \
    _Pragma("unroll")                                                          \
    for (int qb = 0; qb < 2; ++qb) {                                           \
      _Pragma("unroll")                                                        \
      for (int tt = 0; tt < 16; ++tt) {                                        \
        sc0[qb][tt] = exp2_fast(sc0[qb][tt] - mrow[qb]);                       \
        sc1[qb][tt] = exp2_fast(sc1[qb][tt] - mrow[qb]);                       \
      }                                                                        \
      _Pragma("unroll")                                                        \
      for (int m = 0; m < 4; ++m) {                                            \
        pa[qb][0].u[m] = packbf(sc0[qb][2 * m], sc0[qb][2 * m + 1]);           \
        pa[qb][1].u[m] = packbf(sc0[qb][8 + 2 * m], sc0[qb][9 + 2 * m]);       \
        pa[qb][2].u[m] = packbf(sc1[qb][2 * m], sc1[qb][2 * m + 1]);           \
        pa[qb][3].u[m] = packbf(sc1[qb][8 + 2 * m], sc1[qb][9 + 2 * m]);       \
      }                                                                        \
    }                                                                          \
    {                                                                          \
      const char* vbase = (const char*)Vs[CUR];                                \
      __builtin_amdgcn_s_setprio(1);                                           \
      _Pragma("unroll")                                                        \
      for (int kb = 0; kb < 4; ++kb) {                                         \
        int chunk = 2 * kb + hi;                                               \
        int r0 = l31, r1 = 32 + l31;                                           \
        bf16x8 v0 = *reinterpret_cast<const bf16x8*>(                          \
            vbase + r0 * 128 + ((chunk ^ (r0 & 7)) << 4));                     \
        bf16x8 v1 = *reinterpret_cast<const bf16x8*>(                          \
            vbase + r1 * 128 + ((chunk ^ (r1 & 7)) << 4));                     \
        _Pragma("unroll")                                                      \
        for (int qb = 0; qb < 2; ++qb) {                                       \
          o0[qb] = __builtin_amdgcn_mfma_f32_32x32x16_bf16(pa[qb][kb].v, v0,   \
                                                           o0[qb], 0, 0, 0);   \
          o1[qb] = __builtin_amdgcn_mfma_f32_32x32x16_bf16(pa[qb][kb].v, v1,   \
                                                           o1[qb], 0, 0, 0);   \
          ls[qb] = __builtin_amdgcn_mfma_f32_32x32x16_bf16(pa[qb][kb].v,       \
                                                           ones8, ls[qb],      \
                                                           0, 0, 0);           \
        }                                                                      \
      }                                                                        \
      __builtin_amdgcn_s_setprio(0);                                           \
    }                                                                          \
  }

  for (int t = 0; t < NT; t += 2) {
    TILE_STEP(t, 0)
    TILE_STEP(t + 1, 1)
  }
#undef TILE_STEP

  // epilogue: elementwise normalize (ls has o0's exact layout), store
  const int b = bh >> 4, h = bh & 15;
#pragma unroll
  for (int qb = 0; qb < 2; ++qb)
#pragma unroll
    for (int tt = 0; tt < 16; ++tt) {
      int row = (tt & 3) + 8 * (tt >> 2) + 4 * hi;
      float inv = __builtin_amdgcn_rcpf(ls[qb][tt]);
      int qr = qw + qb * 32 + row;
      int64_t base = ((int64_t)(b * S_ + qr)) * D_ + h * HD_ + l31;
      AO[base] = f2bf(o0[qb][tt] * inv);
      AO[base + 32] = f2bf(o1[qb][tt] * inv);
    }
}

extern "C" void kernel_launch(void* const* d_in, const int* in_sizes, int n_in,
                              void* d_out, int out_size, void* d_ws, size_t ws_size,
                              hipStream_t stream) {
  const float* x  = (const float*)d_in[0];
  const float* wq = (const float*)d_in[1];
  const float* bq = (const float*)d_in[2];
  const float* wk = (const float*)d_in[3];
  const float* bk = (const float*)d_in[4];
  const float* wv = (const float*)d_in[5];
  const float* bv = (const float*)d_in[6];
  const float* wo = (const float*)d_in[7];
  const float* bo = (const float*)d_in[8];
  char* ws = (char*)d_ws;
  u16* xb  = (u16*)ws;
  u16* wqb = (u16*)(ws + (16ll << 20));
  u16* wkb = (u16*)(ws + (18ll << 20));
  u16* wvb = (u16*)(ws + (20ll << 20));
  u16* wob = (u16*)(ws + (22ll << 20));
  u16* q   = (u16*)(ws + (24ll << 20));
  u16* k   = (u16*)(ws + (40ll << 20));
  u16* vt  = (u16*)(ws + (56ll << 20));
  u16* ao  = xb;

  convert_kernel<<<12288, 256, 0, stream>>>(x, wq, wk, wv, wo, xb, wqb, wkb, wvb, wob);
  dim3 gg(D_ / 128, M_ / 128);  // natural map: XCD = col-block (weight panel resident)
  gemm_kernel<3><<<gg, 256, 0, stream>>>(xb, wqb, bq, q);   // Q, pre-scaled
  gemm_kernel<0><<<gg, 256, 0, stream>>>(xb, wkb, bk, k);
  gemm_kernel<1><<<gg, 256, 0, stream>>>(xb, wvb, bv, vt);  // V^T
  attn_kernel<<<512, 256, 0, stream>>>(q, k, vt, ao);
  gemm_kernel<2><<<gg, 256, 0, stream>>>(ao, wob, bo, (float*)d_out);
}

// Round 14
// 222.749 us; speedup vs baseline: 4.2633x; 4.2633x over previous
//
#include <hip/hip_runtime.h>
#include <stdint.h>

// B=4, S=2048, D=1024, H=16, HD=64. All inputs fp32.
// convert->bf16; Q(pre-scaled by 0.125*log2e),K in [B,H,S,HD]; V^T [B,H,HD,S];
// flash attention (4 waves x 64 q-rows per block, grid 512 = 2 blocks/CU;
// launch_bounds(256,2) leaves VGPR headroom — R13's (256,4) forced a 128 cap
// and catastrophic scratch spill; 32x32 MFMA swapped QK^T; swap23-permuted K
// staging -> PV A-frags lane-local; register softmax, MFMA denominator,
// dbuf K/V, XCD swizzle) -> ao bf16; out = ao@wo^T+bo fp32.

#define B_ 4
#define S_ 2048
#define D_ 1024
#define H_ 16
#define HD_ 64
#define M_ (B_ * S_)

typedef __bf16 bf16x8 __attribute__((ext_vector_type(8)));
typedef float f32x4 __attribute__((ext_vector_type(4)));
typedef float f32x16 __attribute__((ext_vector_type(16)));
typedef unsigned short u16;
typedef union { bf16x8 v; unsigned u[4]; } bfu;

// 0.125 (1/sqrt(HD)) * log2(e): scores come out in log2 units
#define QSCALE 0.18033688011112042f
#define THR2 11.0f  // defer-max threshold in log2 units

__device__ __forceinline__ u16 f2bf(float f) {
  union { float f; unsigned u; } v; v.f = f;
  unsigned u = v.u;
  u += 0x7fff + ((u >> 16) & 1);
  return (u16)(u >> 16);
}

__device__ __forceinline__ float exp2_fast(float x) {
#if __has_builtin(__builtin_amdgcn_exp2f)
  return __builtin_amdgcn_exp2f(x);
#else
  return __expf(x * 0.69314718056f);
#endif
}

__device__ __forceinline__ unsigned packbf(float a, float b) {
  union { unsigned u; __bf16 h[2]; } v;
  v.h[0] = (__bf16)a; v.h[1] = (__bf16)b;
  return v.u;
}

__device__ __forceinline__ void gl2lds16(const void* g, void* l) {
  __builtin_amdgcn_global_load_lds(
      (const __attribute__((address_space(1))) unsigned int*)g,
      (__attribute__((address_space(3))) unsigned int*)l, 16, 0, 0);
}

// ---------------- convert fp32 -> bf16 ----------------
__global__ __launch_bounds__(256) void convert_kernel(
    const float* __restrict__ x, const float* __restrict__ wq,
    const float* __restrict__ wk, const float* __restrict__ wv,
    const float* __restrict__ wo, u16* __restrict__ xb, u16* __restrict__ wqb,
    u16* __restrict__ wkb, u16* __restrict__ wvb, u16* __restrict__ wob) {
  const int64_t NX = (int64_t)M_ * D_ / 4;
  const int64_t NW = (int64_t)D_ * D_ / 4;
  int64_t i = (int64_t)blockIdx.x * blockDim.x + threadIdx.x;
  const float* src; u16* dst; int64_t off;
  if (i < NX)              { src = x;  dst = xb;  off = i; }
  else if (i < NX + NW)    { src = wq; dst = wqb; off = i - NX; }
  else if (i < NX + 2*NW)  { src = wk; dst = wkb; off = i - NX - NW; }
  else if (i < NX + 3*NW)  { src = wv; dst = wvb; off = i - NX - 2*NW; }
  else                     { src = wo; dst = wob; off = i - NX - 3*NW; }
  float4 v = reinterpret_cast<const float4*>(src)[off];
  ushort4 o;
  o.x = f2bf(v.x); o.y = f2bf(v.y); o.z = f2bf(v.z); o.w = f2bf(v.w);
  reinterpret_cast<ushort4*>(dst)[off] = o;
}

// ---------------- bf16 MFMA GEMM: C = A(MxK) @ Bw(NxK)^T + bias ----------------
// MODE 0: bf16 out [B,H,S,HD] (K proj)   MODE 3: same, scaled by QSCALE (Q proj)
// MODE 1: swapped, bf16 out [B,H,HD,S] (V^T)   MODE 2: fp32 out [M,N] (final)
template <int MODE>
__global__ __launch_bounds__(256) void gemm_kernel(
    const u16* __restrict__ A, const u16* __restrict__ Bw,
    const float* __restrict__ bias, void* __restrict__ out) {
  __shared__ u16 As[128 * 64];
  __shared__ u16 Bs[128 * 64];
  const int tid = threadIdx.x;
  const int lane = tid & 63;
  const int wid = tid >> 6;
  const int row0 = blockIdx.y * 128;
  const int col0 = blockIdx.x * 128;
  const int wr = (wid >> 1) * 64;
  const int wc = (wid & 1) * 64;

  f32x4 acc[4][4] = {};
  const int srow = lane >> 3;
  const int cc = (lane & 7) ^ srow;

  for (int kt = 0; kt < D_; kt += 64) {
    __syncthreads();
    for (int t = 0; t < 4; ++t) {
      int r = (wid * 4 + t) * 8 + srow;
      gl2lds16(A + (int64_t)(row0 + r) * D_ + kt + cc * 8,
               (char*)As + (wid * 4 + t) * 1024);
      gl2lds16(Bw + (int64_t)(col0 + r) * D_ + kt + cc * 8,
               (char*)Bs + (wid * 4 + t) * 1024);
    }
    __syncthreads();

    bf16x8 af[4][2], bfr[4][2];
#pragma unroll
    for (int mi = 0; mi < 4; ++mi)
#pragma unroll
      for (int ks = 0; ks < 2; ++ks) {
        int c = ks * 4 + (lane >> 4);
        int ra = wr + mi * 16 + (lane & 15);
        af[mi][ks] = *reinterpret_cast<const bf16x8*>(
            (char*)As + ra * 128 + ((c ^ (ra & 7)) << 4));
        int rb = wc + mi * 16 + (lane & 15);
        bfr[mi][ks] = *reinterpret_cast<const bf16x8*>(
            (char*)Bs + rb * 128 + ((c ^ (rb & 7)) << 4));
      }
#pragma unroll
    for (int ks = 0; ks < 2; ++ks)
#pragma unroll
      for (int mi = 0; mi < 4; ++mi)
#pragma unroll
        for (int ni = 0; ni < 4; ++ni) {
          if (MODE == 1)
            acc[mi][ni] = __builtin_amdgcn_mfma_f32_16x16x32_bf16(
                bfr[ni][ks], af[mi][ks], acc[mi][ni], 0, 0, 0);
          else
            acc[mi][ni] = __builtin_amdgcn_mfma_f32_16x16x32_bf16(
                af[mi][ks], bfr[ni][ks], acc[mi][ni], 0, 0, 0);
        }
  }

  if (MODE == 0 || MODE == 3) {
    u16* o = (u16*)out;
#pragma unroll
    for (int mi = 0; mi < 4; ++mi)
#pragma unroll
      for (int ni = 0; ni < 4; ++ni) {
        int j = col0 + wc + ni * 16 + (lane & 15);
        float bvv = bias[j];
        int h = j >> 6, hd = j & 63;
#pragma unroll
        for (int r = 0; r < 4; ++r) {
          int i = row0 + wr + mi * 16 + (lane >> 4) * 4 + r;
          int b = i >> 11, s = i & 2047;
          float val = acc[mi][ni][r] + bvv;
          if (MODE == 3) val *= QSCALE;
          o[((int64_t)(b * H_ + h) * S_ + s) * HD_ + hd] = f2bf(val);
        }
      }
  } else if (MODE == 1) {
    u16* o = (u16*)out;
#pragma unroll
    for (int mi = 0; mi < 4; ++mi)
#pragma unroll
      for (int ni = 0; ni < 4; ++ni) {
        int i = row0 + wr + mi * 16 + (lane & 15);
        int b = i >> 11, s = i & 2047;
#pragma unroll
        for (int r = 0; r < 4; ++r) {
          int j = col0 + wc + ni * 16 + (lane >> 4) * 4 + r;
          int h = j >> 6, hd = j & 63;
          o[((int64_t)(b * H_ + h) * HD_ + hd) * S_ + s] = f2bf(acc[mi][ni][r] + bias[j]);
        }
      }
  } else {
    float* o = (float*)out;
#pragma unroll
    for (int mi = 0; mi < 4; ++mi)
#pragma unroll
      for (int ni = 0; ni < 4; ++ni) {
        int j = col0 + wc + ni * 16 + (lane & 15);
        float bvv = bias[j];
#pragma unroll
        for (int r = 0; r < 4; ++r) {
          int i = row0 + wr + mi * 16 + (lane >> 4) * 4 + r;
          o[(int64_t)i * D_ + j] = acc[mi][ni][r] + bvv;
        }
      }
  }
}

// ---------------- flash attention (4 waves x 64 q-rows, 2 blocks/CU) ----------
// grid 512 (XCD-swizzled). Wave owns 64 q-rows (qb=0,1); swap23-permuted K
// staging makes PV A-frags lane-local. launch_bounds(256,2): VGPR cap 256,
// allocator expected to pick ~128 -> 2 blocks co-resident per CU.
__global__ __launch_bounds__(256, 2) void attn_kernel(
    const u16* __restrict__ Q, const u16* __restrict__ Kg,
    const u16* __restrict__ Vt, u16* __restrict__ AO) {
  __shared__ u16 Ks[2][64 * 64];   // swizzled [kv][hd], rows kv-permuted by swap23
  __shared__ u16 Vs[2][64 * 64];   // swizzled [hd][kv], true kv order
  const int tid = threadIdx.x;
  const int lane = tid & 63;
  const int l31 = lane & 31;
  const int hi = lane >> 5;
  const int wid = tid >> 6;        // 0..3
  const int orig = blockIdx.x;     // 512
  const int swz = (orig & 7) * 64 + (orig >> 3);
  const int bh = swz >> 3;
  const int qw = (swz & 7) * 256 + wid * 64;

  // Q as B-operand (32x32x16): qb sub-block q-col = qw + qb*32 + l31
  bf16x8 qf[2][4];
#pragma unroll
  for (int qb = 0; qb < 2; ++qb)
#pragma unroll
    for (int ks = 0; ks < 4; ++ks)
      qf[qb][ks] = *reinterpret_cast<const bf16x8*>(
          Q + ((int64_t)bh * S_ + qw + qb * 32 + l31) * HD_ + ks * 16 + hi * 8);

  bf16x8 ones8;
#pragma unroll
  for (int i = 0; i < 8; ++i) ones8[i] = (__bf16)1.0f;

  f32x16 o0[2] = {}, o1[2] = {}, ls[2] = {};
  float mrow[2] = {-1e30f, -1e30f};

  const int srow = lane >> 3;
  const int cc = (lane & 7) ^ srow;

  // staging: wave wid owns LDS row-groups {2wid, 2wid+1} for K (swap23'd) and V.
  const int lr0 = (wid * 2 + 0) * 8 + srow;
  const int lr1 = (wid * 2 + 1) * 8 + srow;
  const int sr0 = (lr0 & ~12) | ((lr0 & 4) << 1) | ((lr0 & 8) >> 1);  // swap b2,b3
  const int sr1 = (lr1 & ~12) | ((lr1 & 4) << 1) | ((lr1 & 8) >> 1);
  const u16* kp0 = Kg + ((int64_t)bh * S_ + sr0) * HD_ + cc * 8;
  const u16* kp1 = Kg + ((int64_t)bh * S_ + sr1) * HD_ + cc * 8;
  const u16* vp0 = Vt + ((int64_t)bh * HD_ + lr0) * S_ + cc * 8;
  const u16* vp1 = Vt + ((int64_t)bh * HD_ + lr1) * S_ + cc * 8;

  // prologue: stage tile 0 -> buf 0
  gl2lds16(kp0, (char*)Ks[0] + (wid * 2 + 0) * 1024); kp0 += 64 * HD_;
  gl2lds16(kp1, (char*)Ks[0] + (wid * 2 + 1) * 1024); kp1 += 64 * HD_;
  gl2lds16(vp0, (char*)Vs[0] + (wid * 2 + 0) * 1024); vp0 += 64;
  gl2lds16(vp1, (char*)Vs[0] + (wid * 2 + 1) * 1024); vp1 += 64;

  const int NT = S_ / 64;

#define TILE_STEP(T, CUR)                                                      \
  {                                                                            \
    asm volatile("s_waitcnt vmcnt(0)" ::: "memory");                           \
    __builtin_amdgcn_s_barrier();                                              \
    if ((T) + 1 < NT) {                                                        \
      gl2lds16(kp0, (char*)Ks[(CUR) ^ 1] + (wid * 2 + 0) * 1024);              \
      gl2lds16(kp1, (char*)Ks[(CUR) ^ 1] + (wid * 2 + 1) * 1024);              \
      gl2lds16(vp0, (char*)Vs[(CUR) ^ 1] + (wid * 2 + 0) * 1024);              \
      gl2lds16(vp1, (char*)Vs[(CUR) ^ 1] + (wid * 2 + 1) * 1024);              \
      kp0 += 64 * HD_; kp1 += 64 * HD_; vp0 += 64; vp1 += 64;                  \
    }                                                                          \
    f32x16 sc0[2] = {{}, {}}, sc1[2] = {{}, {}};                               \
    {                                                                          \
      const char* kbase = (const char*)Ks[CUR];                                \
      __builtin_amdgcn_s_setprio(1);                                           \
      _Pragma("unroll")                                                        \
      for (int ks = 0; ks < 4; ++ks) {                                         \
        int chunk = 2 * ks + hi;                                               \
        int r0 = l31, r1 = 32 + l31;                                           \
        bf16x8 k0 = *reinterpret_cast<const bf16x8*>(                          \
            kbase + r0 * 128 + ((chunk ^ (r0 & 7)) << 4));                     \
        bf16x8 k1 = *reinterpret_cast<const bf16x8*>(                          \
            kbase + r1 * 128 + ((chunk ^ (r1 & 7)) << 4));                     \
        _Pragma("unroll")                                                      \
        for (int qb = 0; qb < 2; ++qb) {                                       \
          sc0[qb] = __builtin_amdgcn_mfma_f32_32x32x16_bf16(k0, qf[qb][ks],    \
                                                            sc0[qb], 0, 0, 0); \
          sc1[qb] = __builtin_amdgcn_mfma_f32_32x32x16_bf16(k1, qf[qb][ks],    \
                                                            sc1[qb], 0, 0, 0); \
        }                                                                      \
      }                                                                        \
      __builtin_amdgcn_s_setprio(0);                                           \
    }                                                                          \
    float mx[2];                                                               \
    _Pragma("unroll")                                                          \
    for (int qb = 0; qb < 2; ++qb) {                                           \
      float a8[8];                                                             \
      _Pragma("unroll")                                                        \
      for (int i = 0; i < 8; ++i)                                              \
        a8[i] = fmaxf(fmaxf(fmaxf(sc0[qb][2 * i], sc0[qb][2 * i + 1]),         \
                            sc1[qb][2 * i]), sc1[qb][2 * i + 1]);              \
      mx[qb] = fmaxf(fmaxf(fmaxf(fmaxf(a8[0], a8[1]), a8[2]), a8[3]),          \
                     fmaxf(fmaxf(fmaxf(a8[4], a8[5]), a8[6]), a8[7]));         \
    }                                                                          \
    int okd = (mx[0] - mrow[0] <= THR2 && mx[1] - mrow[1] <= THR2) ? 1 : 0;    \
    if (!__all(okd)) {                                                         \
      _Pragma("unroll")                                                        \
      for (int qb = 0; qb < 2; ++qb) {                                         \
        float mxf = fmaxf(mx[qb], __shfl_xor(mx[qb], 32));                     \
        float mnew = fmaxf(mrow[qb], mxf);                                     \
        float al = exp2_fast(mrow[qb] - mnew);                                 \
        mrow[qb] = mnew;                                                       \
        _Pragma("unroll")                                                      \
        for (int tt = 0; tt < 16; ++tt) {                                      \
          float at = __shfl(al, (tt & 3) + 8 * (tt >> 2) + 4 * hi);            \
          o0[qb][tt] *= at; o1[qb][tt] *= at; ls[qb][tt] *= at;                \
        }                                                                      \
      }                                                                        \
    }                                                                          \
    bfu pa[2][4];                                                              \
    _Pragma("unroll")                                                          \
    for (int qb = 0; qb < 2; ++qb) {                                           \
      _Pragma("unroll")                                                        \
      for (int tt = 0; tt < 16; ++tt) {                                        \
        sc0[qb][tt] = exp2_fast(sc0[qb][tt] - mrow[qb]);                       \
        sc1[qb][tt] = exp2_fast(sc1[qb][tt] - mrow[qb]);                       \
      }                                                                        \
      _Pragma("unroll")                                                        \
      for (int m = 0; m < 4; ++m) {                                            \
        pa[qb][0].u[m] = packbf(sc0[qb][2 * m], sc0[qb][2 * m + 1]);           \
        pa[qb][1].u[m] = packbf(sc0[qb][8 + 2 * m], sc0[qb][9 + 2 * m]);       \
        pa[qb][2].u[m] = packbf(sc1[qb][2 * m], sc1[qb][2 * m + 1]);           \
        pa[qb][3].u[m] = packbf(sc1[qb][8 + 2 * m], sc1[qb][9 + 2 * m]);       \
      }                                                                        \
    }                                                                          \
    {                                                                          \
      const char* vbase = (const char*)Vs[CUR];                                \
      __builtin_amdgcn_s_setprio(1);                                           \
      _Pragma("unroll")                                                        \
      for (int kb = 0; kb < 4; ++kb) {                                         \
        int chunk = 2 * kb + hi;                                               \
        int r0 = l31, r1 = 32 + l31;                                           \
        bf16x8 v0 = *reinterpret_cast<const bf16x8*>(                          \
            vbase + r0 * 128 + ((chunk ^ (r0 & 7)) << 4));                     \
        bf16x8 v1 = *reinterpret_cast<const bf16x8*>(                          \
            vbase + r1 * 128 + ((chunk ^ (r1 & 7)) << 4));                     \
        _Pragma("unroll")                                                      \
        for (int qb = 0; qb < 2; ++qb) {                                       \
          o0[qb] = __builtin_amdgcn_mfma_f32_32x32x16_bf16(pa[qb][kb].v, v0,   \
                                                           o0[qb], 0, 0, 0);   \
          o1[qb] = __builtin_amdgcn_mfma_f32_32x32x16_bf16(pa[qb][kb].v, v1,   \
                                                           o1[qb], 0, 0, 0);   \
          ls[qb] = __builtin_amdgcn_mfma_f32_32x32x16_bf16(pa[qb][kb].v,       \
                                                           ones8, ls[qb],      \
                                                           0, 0, 0);           \
        }                                                                      \
      }                                                                        \
      __builtin_amdgcn_s_setprio(0);                                           \
    }                                                                          \
  }

  for (int t = 0; t < NT; t += 2) {
    TILE_STEP(t, 0)
    TILE_STEP(t + 1, 1)
  }
#undef TILE_STEP

  // epilogue: elementwise normalize (ls has o0's exact layout), store
  const int b = bh >> 4, h = bh & 15;
#pragma unroll
  for (int qb = 0; qb < 2; ++qb)
#pragma unroll
    for (int tt = 0; tt < 16; ++tt) {
      int row = (tt & 3) + 8 * (tt >> 2) + 4 * hi;
      float inv = __builtin_amdgcn_rcpf(ls[qb][tt]);
      int qr = qw + qb * 32 + row;
      int64_t base = ((int64_t)(b * S_ + qr)) * D_ + h * HD_ + l31;
      AO[base] = f2bf(o0[qb][tt] * inv);
      AO[base + 32] = f2bf(o1[qb][tt] * inv);
    }
}

extern "C" void kernel_launch(void* const* d_in, const int* in_sizes, int n_in,
                              void* d_out, int out_size, void* d_ws, size_t ws_size,
                              hipStream_t stream) {
  const float* x  = (const float*)d_in[0];
  const float* wq = (const float*)d_in[1];
  const float* bq = (const float*)d_in[2];
  const float* wk = (const float*)d_in[3];
  const float* bk = (const float*)d_in[4];
  const float* wv = (const float*)d_in[5];
  const float* bv = (const float*)d_in[6];
  const float* wo = (const float*)d_in[7];
  const float* bo = (const float*)d_in[8];
  char* ws = (char*)d_ws;
  u16* xb  = (u16*)ws;
  u16* wqb = (u16*)(ws + (16ll << 20));
  u16* wkb = (u16*)(ws + (18ll << 20));
  u16* wvb = (u16*)(ws + (20ll << 20));
  u16* wob = (u16*)(ws + (22ll << 20));
  u16* q   = (u16*)(ws + (24ll << 20));
  u16* k   = (u16*)(ws + (40ll << 20));
  u16* vt  = (u16*)(ws + (56ll << 20));
  u16* ao  = xb;

  convert_kernel<<<12288, 256, 0, stream>>>(x, wq, wk, wv, wo, xb, wqb, wkb, wvb, wob);
  dim3 gg(D_ / 128, M_ / 128);  // natural map: XCD = col-block (weight panel resident)
  gemm_kernel<3><<<gg, 256, 0, stream>>>(xb, wqb, bq, q);   // Q, pre-scaled
  gemm_kernel<0><<<gg, 256, 0, stream>>>(xb, wkb, bk, k);
  gemm_kernel<1><<<gg, 256, 0, stream>>>(xb, wvb, bv, vt);  // V^T
  attn_kernel<<<512, 256, 0, stream>>>(q, k, vt, ao);
  gemm_kernel<2><<<gg, 256, 0, stream>>>(ao, wob, bo, (float*)d_out);
}